// Round 1
// baseline (107.845 us; speedup 1.0000x reference)
//
#include <hip/hip_runtime.h>

#define NB   8192
#define NT   2048
#define OBS  30
#define LCH  128              // chunk length
#define CCH  16               // chunks per row (LCH*CCH == NT)
#define NCHAIN (NB*CCH)

// scratch in static device globals (avoid ws_size assumptions); fully
// rewritten every call before any read -> deterministic.
__device__ float g_p [(size_t)NCHAIN * 32];   // [(c*NB+b)*32 + k] zero-init chunk-final states
__device__ float g_s [(size_t)NCHAIN * 32];   // [(c*NB+b)*32 + k] true chunk-start states
__device__ float g_AL[32 * 32];               // row-major A^L (zero-padded to 32x32)

// One recurrence step on a 32-slot register ring.
// Invariant: before step t, state s_t[i] lives at r[(t+i)&31], i=0..29.
// j == t mod 32 must be compile-time constant (callers fully unroll).
__device__ __forceinline__ float step_ring(float (&r)[32], const float (&wx)[OBS],
                                           int j, float uwf) {
  float a0 = wx[0] * r[(j + 0) & 31];
  float a1 = wx[1] * r[(j + 1) & 31];
  float a2 = wx[2] * r[(j + 2) & 31];
  float a3 = uwf;
  #pragma unroll
  for (int i = 3; i < OBS; i += 3) {
    a0 += wx[i]     * r[(j + i)     & 31];
    a1 += wx[i + 1] * r[(j + i + 1) & 31];
    a2 += wx[i + 2] * r[(j + i + 2) & 31];
  }
  float out = (a0 + a1) + (a2 + a3);
  r[(j + 30) & 31] = out;   // becomes s_{t+1}[29]
  return out;
}

// ---- kernel 0: A^L (homogeneous L-step transition), 32x32 zero-padded ----
__global__ void k_al(const float* __restrict__ Wx) {
  int k = threadIdx.x;
  if (k >= 32) return;
  float wx[OBS];
  #pragma unroll
  for (int i = 0; i < OBS; ++i) wx[i] = Wx[i];
  float r[32];
  #pragma unroll
  for (int i = 0; i < 32; ++i) r[i] = (k < OBS && i == k) ? 1.f : 0.f;
  #pragma unroll 1
  for (int blk = 0; blk < LCH / 32; ++blk) {
    #pragma unroll
    for (int j = 0; j < 32; ++j) step_ring(r, wx, j, 0.f);
  }
  // final state = column k of A^L (LCH % 32 == 0 -> state i at r[i])
  #pragma unroll
  for (int i = 0; i < OBS; ++i) g_AL[i * 32 + k] = r[i];
  g_AL[30 * 32 + k] = 0.f;   // pad rows
  g_AL[31 * 32 + k] = 0.f;
}

// ---- pass A: per-(b,c) particular (zero-init) chunk-final state ----
__global__ void __launch_bounds__(256) k_passA(const float* __restrict__ u,
                                               const float* __restrict__ Wx,
                                               const float* __restrict__ Wf) {
  int n = blockIdx.x * 256 + threadIdx.x;     // chain = b*CCH + c
  int b = n >> 4, c = n & (CCH - 1);
  float wx[OBS];
  #pragma unroll
  for (int i = 0; i < OBS; ++i) wx[i] = Wx[i];
  float wf = Wf[0];
  float r[32];
  #pragma unroll
  for (int i = 0; i < 32; ++i) r[i] = 0.f;
  const float4* up = (const float4*)(u + (size_t)n * LCH);
  #pragma unroll 1
  for (int blk = 0; blk < LCH / 32; ++blk) {
    #pragma unroll
    for (int q = 0; q < 8; ++q) {
      float4 u4 = up[blk * 8 + q];
      step_ring(r, wx, q * 4 + 0, wf * u4.x);
      step_ring(r, wx, q * 4 + 1, wf * u4.y);
      step_ring(r, wx, q * 4 + 2, wf * u4.z);
      step_ring(r, wx, q * 4 + 3, wf * u4.w);
    }
  }
  r[30] = 0.f; r[31] = 0.f;
  float4* pv = (float4*)(g_p + ((size_t)c * NB + b) * 32);
  #pragma unroll
  for (int q = 0; q < 8; ++q)
    pv[q] = make_float4(r[4 * q], r[4 * q + 1], r[4 * q + 2], r[4 * q + 3]);
}

// ---- pass B: scan over chunks: s_{c+1} = A^L s_c + p_c (32 lanes per row) ----
__global__ void __launch_bounds__(256) k_scan(const float* __restrict__ x0) {
  int tid = blockIdx.x * 256 + threadIdx.x;
  int b = tid >> 5, k = tid & 31;
  float arow[32];
  #pragma unroll
  for (int j = 0; j < 32; ++j) arow[j] = g_AL[k * 32 + j];
  float s = (k < OBS) ? x0[b * OBS + k] : 0.f;
  #pragma unroll 1
  for (int c = 0; c < CCH; ++c) {
    size_t off = ((size_t)c * NB + b) * 32 + k;
    g_s[off] = s;
    float acc = g_p[off];
    #pragma unroll
    for (int j = 0; j < 32; ++j) acc += arow[j] * __shfl(s, j, 32);
    s = acc;
  }
}

// ---- pass C: re-run each chunk from its true start state, write outputs ----
__global__ void __launch_bounds__(256) k_passC(const float* __restrict__ u,
                                               const float* __restrict__ Wx,
                                               const float* __restrict__ Wf,
                                               float* __restrict__ out) {
  int n = blockIdx.x * 256 + threadIdx.x;
  int b = n >> 4, c = n & (CCH - 1);
  float wx[OBS];
  #pragma unroll
  for (int i = 0; i < OBS; ++i) wx[i] = Wx[i];
  float wf = Wf[0];
  float r[32];
  const float4* sp = (const float4*)(g_s + ((size_t)c * NB + b) * 32);
  #pragma unroll
  for (int q = 0; q < 8; ++q) {
    float4 v = sp[q];
    r[4 * q] = v.x; r[4 * q + 1] = v.y; r[4 * q + 2] = v.z; r[4 * q + 3] = v.w;
  }
  const float4* up = (const float4*)(u + (size_t)n * LCH);
  float4*       op = (float4*)(out + (size_t)n * LCH);
  #pragma unroll 1
  for (int blk = 0; blk < LCH / 32; ++blk) {
    #pragma unroll
    for (int q = 0; q < 8; ++q) {
      float4 u4 = up[blk * 8 + q];
      float4 o4;
      o4.x = step_ring(r, wx, q * 4 + 0, wf * u4.x);
      o4.y = step_ring(r, wx, q * 4 + 1, wf * u4.y);
      o4.z = step_ring(r, wx, q * 4 + 2, wf * u4.z);
      o4.w = step_ring(r, wx, q * 4 + 3, wf * u4.w);
      op[blk * 8 + q] = o4;
    }
  }
}

extern "C" void kernel_launch(void* const* d_in, const int* in_sizes, int n_in,
                              void* d_out, int out_size, void* d_ws, size_t ws_size,
                              hipStream_t stream) {
  const float* u  = (const float*)d_in[0];
  const float* x0 = (const float*)d_in[1];
  const float* Wx = (const float*)d_in[2];
  const float* Wf = (const float*)d_in[3];
  float* out = (float*)d_out;

  hipLaunchKernelGGL(k_al,    dim3(1),            dim3(64),  0, stream, Wx);
  hipLaunchKernelGGL(k_passA, dim3(NCHAIN / 256), dim3(256), 0, stream, u, Wx, Wf);
  hipLaunchKernelGGL(k_scan,  dim3(NB * 32 / 256),dim3(256), 0, stream, x0);
  hipLaunchKernelGGL(k_passC, dim3(NCHAIN / 256), dim3(256), 0, stream, u, Wx, Wf, out);
}